// Round 3
// baseline (5820.149 us; speedup 1.0000x reference)
//
#include <hip/hip_runtime.h>
#include <cmath>

// 11-layer stacked LSTM, S=512, B=256, H=106 (gate dim 424).
// One block per batch row (grid=256), thread j owns gate row j.
// R3 vs R2: weight registers are 27 NAMED half8 ext-vectors (no array, no
// union) so SROA cannot leave an alloca -> guaranteed VGPR residency
// (R2 reported VGPR_Count=80 for a kernel needing ~130 -> scratch suspected).
// Block 512 (8 waves, 2/SIMD balanced), __launch_bounds__(512,1).

namespace {
constexpr int H    = 106;
constexpr int G4   = 424;   // 4*H
constexpr int SEQ  = 512;
constexpr int BB   = 256;

using half8  = __attribute__((ext_vector_type(8))) _Float16;
using half2v = __attribute__((ext_vector_type(2))) _Float16;

__device__ __forceinline__ float fdot2(half2v a, half2v b, float acc) {
#if __has_builtin(__builtin_amdgcn_fdot2)
    return __builtin_amdgcn_fdot2(a, b, acc, false);
#else
    return fmaf((float)a[0], (float)b[0], fmaf((float)a[1], (float)b[1], acc));
#endif
}

__device__ __forceinline__ float fast_sigmoid(float x) {
    return 1.0f / (1.0f + __expf(-x));
}
__device__ __forceinline__ float fast_tanh(float x) {
    float t = __expf(2.0f * x);
    return 1.0f - 2.0f / (t + 1.0f);
}

// Build one 8-wide f16 weight chunk for u-layout:
// u[0..107] = x (K_IN vals, zero pad), u[108..213] = h, u[214..215] = pad.
template <int K_IN>
__device__ __forceinline__ half8 make_w(const float* __restrict__ wx,
                                        const float* __restrict__ wh, int q) {
    half8 r;
    #pragma unroll
    for (int e = 0; e < 8; ++e) {
        int k = 8 * q + e;
        float v;
        if (k < K_IN)            v = wx[k];
        else if (k < 108)        v = 0.0f;
        else if (k < 108 + H)    v = wh[k - 108];
        else                     v = 0.0f;
        r[e] = (_Float16)v;
    }
    return r;
}

#define W_LIST(X) \
    X(0) X(1) X(2) X(3) X(4) X(5) X(6) X(7) X(8) X(9) X(10) X(11) X(12) X(13) \
    X(14) X(15) X(16) X(17) X(18) X(19) X(20) X(21) X(22) X(23) X(24) X(25) X(26)

template <int K_IN>
__global__ __launch_bounds__(512, 1)
void lstm_layer(const float* __restrict__ x,    // (S, B, K_IN)
                float* __restrict__ y,          // (S, B, H)
                const float* __restrict__ Wih,  // (4H, K_IN)
                const float* __restrict__ Whh,  // (4H, H)
                const float* __restrict__ bih,  // (4H)
                const float* __restrict__ bhh)  // (4H)
{
    const int b = blockIdx.x;    // batch row
    const int j = threadIdx.x;   // gate row (j < 424 active in dot)

    __shared__ __align__(16) _Float16 su[216];
    __shared__ float gates[G4];

    // ---- 27 named half8 weight registers ----
#define DECL_W(Q) half8 w##Q{};
    W_LIST(DECL_W)
#undef DECL_W
    float bias = 0.0f;
    if (j < G4) {
        const float* wx = Wih + (size_t)j * K_IN;
        const float* wh = Whh + (size_t)j * H;
#define LOAD_W(Q) w##Q = make_w<K_IN>(wx, wh, Q);
        W_LIST(LOAD_W)
#undef LOAD_W
        bias = bih[j] + bhh[j];
    }

    // ---- init state ----
    if (j < 216) su[j] = (_Float16)0.0f;
    __syncthreads();
    if (j < K_IN) su[j] = (_Float16)x[(size_t)b * K_IN + j];   // x_0
    float c = 0.0f;
    const int gate_id = j / H;           // 0:i 1:f 2:g 3:o
    const size_t xstride = (size_t)BB * K_IN;
    const float* xpre_ptr = x + (size_t)BB * K_IN + (size_t)b * K_IN + (j - 128);
    float* yptr = y + (size_t)b * H + j;
    __syncthreads();

    for (int s = 0; s < SEQ; ++s) {
        // prefetch x_{s+1} (latency hidden under the dot phase)
        const bool pre = (s + 1 < SEQ) && (j >= 128) && (j < 128 + K_IN);
        float xpre = 0.0f;
        if (pre) xpre = xpre_ptr[(size_t)s * xstride];

        // ---- phase A: g = bias + W.[x;h], activation ----
        if (j < G4) {
            float a0 = 0.0f, a1 = 0.0f, a2 = 0.0f, a3 = 0.0f;
#define CHUNK(Q) { \
            half8 u8 = *reinterpret_cast<const half8*>(&su[8 * (Q)]); \
            a0 = fdot2(__builtin_shufflevector(w##Q, w##Q, 0, 1), \
                       __builtin_shufflevector(u8,   u8,   0, 1), a0); \
            a1 = fdot2(__builtin_shufflevector(w##Q, w##Q, 2, 3), \
                       __builtin_shufflevector(u8,   u8,   2, 3), a1); \
            a2 = fdot2(__builtin_shufflevector(w##Q, w##Q, 4, 5), \
                       __builtin_shufflevector(u8,   u8,   4, 5), a2); \
            a3 = fdot2(__builtin_shufflevector(w##Q, w##Q, 6, 7), \
                       __builtin_shufflevector(u8,   u8,   6, 7), a3); }
            W_LIST(CHUNK)
#undef CHUNK
            float g = bias + ((a0 + a1) + (a2 + a3));
            gates[j] = (gate_id == 2) ? fast_tanh(g) : fast_sigmoid(g);
        }
        __syncthreads();

        // ---- phase B: state update + h broadcast + output ----
        if (j < H) {
            float gi = gates[j];
            float gf = gates[H + j];
            float gg = gates[2 * H + j];
            float go = gates[3 * H + j];
            c = fmaf(gf, c, gi * gg);
            float h = go * fast_tanh(c);
            su[108 + j] = (_Float16)h;
            yptr[(size_t)s * BB * H] = h;
        }
        if (pre) su[j - 128] = (_Float16)xpre;
        __syncthreads();
    }
}
}  // namespace

extern "C" void kernel_launch(void* const* d_in, const int* in_sizes, int n_in,
                              void* d_out, int out_size, void* d_ws, size_t ws_size,
                              hipStream_t stream) {
    const float* noise = (const float*)d_in[0];  // (512,256,100)
    const float* W_ih0 = (const float*)d_in[1];  // (424,100)
    const float* W_hh0 = (const float*)d_in[2];  // (424,106)
    const float* b_ih0 = (const float*)d_in[3];  // (424)
    const float* b_hh0 = (const float*)d_in[4];  // (424)
    const float* W_ih  = (const float*)d_in[5];  // (10,424,106)
    const float* W_hh  = (const float*)d_in[6];  // (10,424,106)
    const float* b_ih  = (const float*)d_in[7];  // (10,424)
    const float* b_hh  = (const float*)d_in[8];  // (10,424)

    float* out = (float*)d_out;                  // (512,256,106) f32
    float* ws  = (float*)d_ws;                   // scratch ping-pong buffer

    dim3 grid(BB), block(512);

    // Layer 0 (input dim 100) -> d_out
    lstm_layer<100><<<grid, block, 0, stream>>>(noise, out, W_ih0, W_hh0, b_ih0, b_hh0);

    // Layers 1..10 (input dim 106), ping-pong ws/out; last lands in out.
    const float* src = out;
    for (int l = 0; l < 10; ++l) {
        float* dst = ((l & 1) == 0) ? ws : out;
        lstm_layer<106><<<grid, block, 0, stream>>>(
            src, dst,
            W_ih + (size_t)l * G4 * H,
            W_hh + (size_t)l * G4 * H,
            b_ih + (size_t)l * G4,
            b_hh + (size_t)l * G4);
        src = dst;
    }
}